// Round 7
// baseline (272.230 us; speedup 1.0000x reference)
//
#include <hip/hip_runtime.h>
#include <cstdint>
#include <cstddef>

#define BETA 5.5f
#define ALPHA 0.5f

constexpr int D   = 512;     // feature dim
constexpr int NB  = 4096;    // queries
constexpr int NK  = 16384;   // keys
constexpr int BQ  = 64;      // query tile per block
constexpr int BN  = 64;      // key chunk
constexpr int NSPLIT = 4;
constexpr int NRANGE = NK / NSPLIT;   // 4096
constexpr int CHUNKS = NRANGE / BN;   // 64
constexpr int KROW = D + 8;           // padded LDS row (bf16), 1040 B
constexpr int PROW = BN + 8;          // padded P row: 72

typedef __attribute__((ext_vector_type(8)))  short    short8;
typedef __attribute__((ext_vector_type(4)))  float    floatx4;
typedef __attribute__((ext_vector_type(4)))  uint32_t uint4v;
typedef __attribute__((ext_vector_type(2)))  uint32_t uint2v;

__device__ inline uint32_t f2bf1(float f) {
  union { float f; uint32_t u; } v; v.f = f;
  return (v.u + 0x7FFFu + ((v.u >> 16) & 1u)) >> 16;   // RNE
}
__device__ inline uint32_t pack2(float a, float b) {
  return f2bf1(a) | (f2bf1(b) << 16);
}

__device__ inline void load_lds16(const void* g, void* l) {
  __builtin_amdgcn_global_load_lds(
      (const __attribute__((address_space(1))) uint32_t*)g,
      (__attribute__((address_space(3))) uint32_t*)l, 16, 0, 0);
}

// spin until *f >= tgt. All 64 lanes read same LDS addr (broadcast, no
// conflict); s_sleep(1) between polls keeps the LDS port free.
__device__ inline void spin_ge(volatile uint32_t* f, uint32_t tgt) {
  while (*f < tgt) __builtin_amdgcn_s_sleep(1);
  asm volatile("" ::: "memory");   // compiler fence: no op hoisting above
}
__device__ inline void bump(uint32_t* f) {
  asm volatile("" ::: "memory");   // all prior mem ops stay prior
  if ((threadIdx.x & 63) == 0) atomicAdd(f, 1u);
}

// ---------------- normalize Q -> Qn (bf16), and init out = Q ----------------
__global__ void norm_q_kernel(const float* __restrict__ q,
                              float* __restrict__ out,
                              unsigned short* __restrict__ Qn) {
  const int wave = threadIdx.x >> 6, lane = threadIdx.x & 63;
  const int row = blockIdx.x * 4 + wave;
  const float4* qr = (const float4*)(q + (size_t)row * D);
  float4 a = qr[lane * 2];
  float4 b = qr[lane * 2 + 1];
  float ss = a.x*a.x + a.y*a.y + a.z*a.z + a.w*a.w
           + b.x*b.x + b.y*b.y + b.z*b.z + b.w*b.w;
#pragma unroll
  for (int m = 32; m >= 1; m >>= 1) ss += __shfl_xor(ss, m, 64);
  const float sc = 1.0f / fmaxf(sqrtf(ss), 1e-12f);
  float4* orow = (float4*)(out + (size_t)row * D);
  orow[lane * 2]     = a;
  orow[lane * 2 + 1] = b;
  uint4v w;
  w.x = pack2(a.x*sc, a.y*sc); w.y = pack2(a.z*sc, a.w*sc);
  w.z = pack2(b.x*sc, b.y*sc); w.w = pack2(b.z*sc, b.w*sc);
  *(uint4v*)(Qn + (size_t)row * D + lane * 8) = w;
}

// ------ normalize K -> Kn (bf16 row-major) + KnT (bf16 transposed) ----------
__global__ void norm_k_kernel(const float* __restrict__ k,
                              unsigned short* __restrict__ Kn,
                              unsigned short* __restrict__ KnT) {
  __shared__ unsigned short tile[64 * KROW];
  const int wave = threadIdx.x >> 6, lane = threadIdx.x & 63;
  const int n0 = blockIdx.x * 64;
#pragma unroll
  for (int i = 0; i < 4; ++i) {
    const int rl = wave * 4 + i;
    const int n  = n0 + rl;
    const float4* kr = (const float4*)(k + (size_t)n * D);
    float4 a = kr[lane * 2], b = kr[lane * 2 + 1];
    float ss = a.x*a.x + a.y*a.y + a.z*a.z + a.w*a.w
             + b.x*b.x + b.y*b.y + b.z*b.z + b.w*b.w;
#pragma unroll
    for (int m = 32; m >= 1; m >>= 1) ss += __shfl_xor(ss, m, 64);
    const float sc = 1.0f / fmaxf(sqrtf(ss), 1e-12f);
    uint4v w;
    w.x = pack2(a.x*sc, a.y*sc); w.y = pack2(a.z*sc, a.w*sc);
    w.z = pack2(b.x*sc, b.y*sc); w.w = pack2(b.z*sc, b.w*sc);
    *(uint4v*)(Kn + (size_t)n * D + lane * 8) = w;
    *(uint4v*)&tile[rl * KROW + lane * 8]     = w;
  }
  __syncthreads();
  const int dsub = threadIdx.x >> 3;        // 0..127
  const int nl   = (threadIdx.x & 7) * 8;   // 0..56
#pragma unroll
  for (int iter = 0; iter < 4; ++iter) {
    const int d = iter * 128 + dsub;
    uint4v w;
    w.x = (uint32_t)tile[(nl+0)*KROW + d] | ((uint32_t)tile[(nl+1)*KROW + d] << 16);
    w.y = (uint32_t)tile[(nl+2)*KROW + d] | ((uint32_t)tile[(nl+3)*KROW + d] << 16);
    w.z = (uint32_t)tile[(nl+4)*KROW + d] | ((uint32_t)tile[(nl+5)*KROW + d] << 16);
    w.w = (uint32_t)tile[(nl+6)*KROW + d] | ((uint32_t)tile[(nl+7)*KROW + d] << 16);
    *(uint4v*)(KnT + (size_t)d * NK + n0 + nl) = w;
  }
}

// ---------------- fused: S = Qn Kn^T chunk, P = exp, O += P Kn --------------
// v8: BARRIER-FREE producer/consumer (LDS flag handoff). R6 accounting
// showed each wave idle ~60% of its region with idle windows coinciding
// (block-wide barrier at 2 waves/SIMD = lockstep). Structural facts:
// K_lds is staged AND consumed only by S-waves; P is the only S->O medium.
// So the block barrier is replaced by monotonic LDS counters:
//   kcnt[buf]  += 1 per S-wave when its 16-row DMA into buf has LANDED
//   kdone[buf] += 1 per S-wave when its reads of the chunk are consumed
//   pprod[slot]+= 1 per S-wave after P slice written + lgkm-drained
//   pcons[slot]+= 1 per O-wave after P(r) fully consumed
// P_lds deepened to 3 slots (depth decouples S from O). Exactly one
// __syncthreads (after flag init). Counters monotonic -> deadlock-free;
// every flag-set is preceded by the wait that makes its data visible
// (vmcnt(16): PREVIOUS chunk's 16 DMA loads drained, current stays in
// flight; lgkmcnt(0) before pprod). Numerics identical to R6.
__global__ __launch_bounds__(512, 2) void fused_kernel(
    const unsigned short* __restrict__ Qn,
    const unsigned short* __restrict__ Kn,
    const unsigned short* __restrict__ KnT,
    float* __restrict__ out) {
  __shared__ unsigned short K_lds[2][BN * KROW];   // 133.1 KB (S-only)
  __shared__ unsigned short P_lds[3][BQ * PROW];   // 27.6 KB, 3-slot ring
  __shared__ uint32_t flags[12];                   // kcnt[2],kdone[2],pprod[3],pcons[3]

  const int tid  = threadIdx.x;
  const int wave = tid >> 6, lane = tid & 63;
  const int l15  = lane & 15, quad = lane >> 4;
  const int nsplit = blockIdx.x & (NSPLIT - 1);
  const int qtile  = blockIdx.x >> 2;           // 0..63
  const int q0     = qtile * BQ;
  const int nbase  = nsplit * NRANGE;

  uint32_t* kcnt  = &flags[0];
  uint32_t* kdone = &flags[2];
  uint32_t* pprod = &flags[4];
  uint32_t* pcons = &flags[7];

  if (tid < 12) flags[tid] = 0;
  __syncthreads();                 // the ONLY block barrier

  if (wave < 4) {
    // ================= S-producer: GEMM1 + exp -> P_lds ===================
    const int sw = wave;
    const int qh = wave & 1, nh = wave >> 1;
    short8 qf[2][16];              // 32 q-cols x 512 k -> 128 VGPR
    {
      const unsigned short* qrow0 = Qn + (size_t)(q0 + qh * 32 + l15) * D + quad * 8;
#pragma unroll
      for (int qt = 0; qt < 2; ++qt)
#pragma unroll
        for (int kb = 0; kb < 16; ++kb)
          qf[qt][kb] = *(const short8*)(qrow0 + (size_t)qt * 16 * D + kb * 32);
    }

    floatx4 sacc[2][2];

    auto stage = [&](int ch, int buf) {
#pragma unroll
      for (int i = 0; i < 16; ++i) {
        const int row = sw * 16 + i;
        load_lds16(Kn + (size_t)(nbase + ch * BN + row) * D + lane * 8,
                   &K_lds[buf][row * KROW]);
      }
    };
    auto a_read8 = [&](int buf, int kb0, short8* af) {
#pragma unroll
      for (int i = 0; i < 4; ++i) {
        af[2*i]   = *(const short8*)&K_lds[buf][(nh*32 +      l15) * KROW + (kb0+i)*32 + quad*8];
        af[2*i+1] = *(const short8*)&K_lds[buf][(nh*32 + 16 + l15) * KROW + (kb0+i)*32 + quad*8];
      }
    };
    auto g1c = [&](const short8* af, int kb0) {
      __builtin_amdgcn_s_setprio(1);
#pragma unroll
      for (int i = 0; i < 4; ++i) {
        sacc[0][0] = __builtin_amdgcn_mfma_f32_16x16x32_bf16(af[2*i],   qf[0][kb0+i], sacc[0][0], 0, 0, 0);
        sacc[0][1] = __builtin_amdgcn_mfma_f32_16x16x32_bf16(af[2*i],   qf[1][kb0+i], sacc[0][1], 0, 0, 0);
        sacc[1][0] = __builtin_amdgcn_mfma_f32_16x16x32_bf16(af[2*i+1], qf[0][kb0+i], sacc[1][0], 0, 0, 0);
        sacc[1][1] = __builtin_amdgcn_mfma_f32_16x16x32_bf16(af[2*i+1], qf[1][kb0+i], sacc[1][1], 0, 0, 0);
      }
      __builtin_amdgcn_s_setprio(0);
    };
    auto gemm1_region = [&](int buf) {
#pragma unroll
      for (int nt = 0; nt < 2; ++nt)
#pragma unroll
        for (int qt = 0; qt < 2; ++qt) sacc[nt][qt] = (floatx4){0.f, 0.f, 0.f, 0.f};
      short8 afA[8], afB[8];
      a_read8(buf, 0, afA);              // depth-2 operand pipeline
      a_read8(buf, 4, afB);
      g1c(afA, 0);
      a_read8(buf, 8, afA);
      g1c(afB, 4);
      a_read8(buf, 12, afB);
      g1c(afA, 8);
      g1c(afB, 12);
    };
    auto exp_pw = [&](int slot) {
#pragma unroll
      for (int qt = 0; qt < 2; ++qt)
#pragma unroll
        for (int nt = 0; nt < 2; ++nt) {
          const floatx4 s = sacc[nt][qt];
          uint2v w;
          w.x = pack2(__expf(BETA * (s[0] - 1.f)), __expf(BETA * (s[1] - 1.f)));
          w.y = pack2(__expf(BETA * (s[2] - 1.f)), __expf(BETA * (s[3] - 1.f)));
          *(uint2v*)&P_lds[slot][(qh*32 + qt*16 + l15) * PROW + nh*32 + nt*16 + quad*4] = w;
        }
    };

    // prologue: stage chunk 0 and 1; credit chunk 0 when landed
    stage(0, 0);
    asm volatile("s_waitcnt vmcnt(0)" ::: "memory");  // qf + stage(0) landed
    bump(&kcnt[0]);
    stage(1, 1);                                      // in flight

#pragma unroll 1
    for (uint32_t p = 0; p < CHUNKS; ++p) {
      const int buf = p & 1, slot = p % 3;
      spin_ge(&kcnt[buf], 4 * (p >> 1) + 4);    // chunk p staged by all 4
      gemm1_region(buf);                         // S(p) into sacc
      bump(&kdone[buf]);                         // my reads of chunk p done
      if (p + 2 < CHUNKS) {
        spin_ge(&kdone[buf], 4 * (p >> 1) + 4);  // all 4 done reading buf
        stage(p + 2, buf);                       // overwrite; 16 loads issued
        asm volatile("s_waitcnt vmcnt(16)" ::: "memory"); // chunk p+1 landed
        bump(&kcnt[buf ^ 1]);
      } else if (p + 1 < CHUNKS) {
        asm volatile("s_waitcnt vmcnt(0)" ::: "memory");  // last chunk landed
        bump(&kcnt[buf ^ 1]);
      }
      spin_ge(&pcons[slot], 4 * (p / 3));        // slot's old occupant consumed
      exp_pw(slot);                              // P(p) -> slot
      asm volatile("s_waitcnt lgkmcnt(0)" ::: "memory"); // P writes visible
      bump(&pprod[slot]);
    }
    // S-waves exit
  } else {
    // ================= O-consumer: GEMM2 + epilogue =======================
    const int w4 = wave - 4;               // d-slice [w4*128, +128)
    floatx4 oacc[4][8] = {};               // 64q x 128d
    short8 ktf[2][8];                      // 64 reg
    const unsigned short* ktb = KnT + (size_t)(w4 * 128 + l15) * NK + nbase + quad * 8;

    auto ldKT = [&](short8* kt, int c, int kb2) {
#pragma unroll
      for (int td = 0; td < 8; ++td)
        kt[td] = *(const short8*)(ktb + (size_t)td * 16 * NK + c * BN + kb2 * 32);
    };
    auto pf_read = [&](int slot, int kb2, short8* pf) {
#pragma unroll
      for (int tr = 0; tr < 4; ++tr)
        pf[tr] = *(const short8*)&P_lds[slot][(tr*16 + l15) * PROW + kb2*32 + quad*8];
    };
    auto g2c = [&](const short8* pf, const short8* kt) {
      __builtin_amdgcn_s_setprio(1);
#pragma unroll
      for (int td = 0; td < 8; ++td)
#pragma unroll
        for (int tr = 0; tr < 4; ++tr)
          oacc[tr][td] = __builtin_amdgcn_mfma_f32_16x16x32_bf16(
              pf[tr], kt[td], oacc[tr][td], 0, 0, 0);
      __builtin_amdgcn_s_setprio(0);
    };

    ldKT(ktf[0], 0, 0); ldKT(ktf[1], 0, 1);   // chunk 0 ktf in flight

#pragma unroll 1
    for (uint32_t r = 0; r < CHUNKS; ++r) {
      const int slot = r % 3;
      spin_ge(&pprod[slot], 4 * (r / 3) + 4);  // P(r) written by all 4 S
      short8 pf0[4], pf1[4];
      pf_read(slot, 0, pf0);
      pf_read(slot, 1, pf1);
      g2c(pf0, ktf[0]);                   // compiler: counted vmcnt for ktf
      if (r + 1 < CHUNKS) ldKT(ktf[0], r + 1, 0);
      g2c(pf1, ktf[1]);
      if (r + 1 < CHUNKS) ldKT(ktf[1], r + 1, 1);
      bump(&pcons[slot]);                 // P(r) consumed
    }

    // ---- epilogue: out += ALPHA * O (out pre-init to Q) ----
    const int colbase = w4 * 128 + l15;
#pragma unroll
    for (int tr = 0; tr < 4; ++tr)
#pragma unroll
      for (int td = 0; td < 8; ++td)
#pragma unroll
        for (int r4 = 0; r4 < 4; ++r4)
          atomicAdd(out + (size_t)(q0 + tr*16 + quad*4 + r4) * D + colbase + td*16,
                    ALPHA * oacc[tr][td][r4]);
  }
}

extern "C" void kernel_launch(void* const* d_in, const int* in_sizes, int n_in,
                              void* d_out, int out_size, void* d_ws, size_t ws_size,
                              hipStream_t stream) {
  (void)in_sizes; (void)n_in; (void)out_size; (void)ws_size;
  const float* q = (const float*)d_in[0];
  const float* k = (const float*)d_in[1];
  float* out = (float*)d_out;
  unsigned short* Qn  = (unsigned short*)d_ws;          //  4 MB
  unsigned short* Kn  = Qn + (size_t)NB * D;            // 16 MB
  unsigned short* KnT = Kn + (size_t)NK * D;            // 16 MB  (total 36 MB)

  hipLaunchKernelGGL(norm_q_kernel, dim3(NB / 4),  dim3(256),  0, stream, q, out, Qn);
  hipLaunchKernelGGL(norm_k_kernel, dim3(NK / 64), dim3(1024), 0, stream, k, Kn, KnT);
  hipLaunchKernelGGL(fused_kernel, dim3((NB / BQ) * NSPLIT), dim3(512), 0, stream,
                     Qn, Kn, KnT, out);
}